// Round 1
// baseline (32165.564 us; speedup 1.0000x reference)
//
#include <hip/hip_runtime.h>
#include <hip/hip_cooperative_groups.h>

namespace cg = cooperative_groups;

typedef unsigned short u16;
typedef short short8 __attribute__((ext_vector_type(8)));
typedef float f32x4 __attribute__((ext_vector_type(4)));

#define Bsz 32
#define Tsz 512
#define Dsz 1024
#define Usz 1024
#define Gsz 4096   // 4*U

// ---- bf16 helpers (manual RNE; avoids header/type friction) ----
static __device__ __forceinline__ u16 f2bf(float f) {
    unsigned int u = __float_as_uint(f);
    unsigned int lsb = (u >> 16) & 1u;
    u += 0x7fffu + lsb;
    return (u16)(u >> 16);
}
static __device__ __forceinline__ float bf2f(u16 b) {
    return __uint_as_float(((unsigned int)b) << 16);
}

// =====================================================================
// Pack kernels: build MFMA-fragment-ordered bf16 buffers.
// A-frag (16x16x32): lane L holds A[m = mt*16 + (L&15)][k = kb*32 + (L>>4)*8 + j], j=0..7
// B-frag:            lane L holds B[k = kb*32 + (L>>4)*8 + j][n = nt*16 + (L&15)]
// Flat layout: buf[((tile*32 + kb)*64 + L)*8 + j]  -> lane-contiguous 16B chunks.
// =====================================================================

// X (B,T,D) fp32 row-major, row m = b*T+t  ->  Af, 1024 M-tiles
__global__ __launch_bounds__(256) void pack_a(const float* __restrict__ x, u16* __restrict__ Af) {
    size_t tid = (size_t)blockIdx.x * 256 + threadIdx.x;   // 1024*32*64 = 2,097,152
    int L = (int)(tid & 63);
    size_t mtkb = tid >> 6;
    int kb = (int)(mtkb & 31);
    int mt = (int)(mtkb >> 5);
    int m  = mt * 16 + (L & 15);
    int d0 = kb * 32 + (L >> 4) * 8;
    const float* src = x + (size_t)m * Dsz + d0;   // 32B-aligned, 8 consecutive floats
    short8 v;
#pragma unroll
    for (int j = 0; j < 8; ++j) v[j] = (short)f2bf(src[j]);
    *(short8*)(Af + tid * 8) = v;
}

// W (D,4U) fp32 row-major -> Bf, 256 N-tiles (natural column order)
__global__ __launch_bounds__(256) void pack_b(const float* __restrict__ W, u16* __restrict__ Bf) {
    size_t tid = (size_t)blockIdx.x * 256 + threadIdx.x;   // 256*32*64 = 524,288
    int L = (int)(tid & 63);
    size_t ntkb = tid >> 6;
    int kb = (int)(ntkb & 31);
    int nt = (int)(ntkb >> 5);
    int n  = nt * 16 + (L & 15);
    int k0 = kb * 32 + (L >> 4) * 8;
    short8 v;
#pragma unroll
    for (int j = 0; j < 8; ++j) v[j] = (short)f2bf(W[(size_t)(k0 + j) * Gsz + n]);
    *(short8*)(Bf + tid * 8) = v;
}

// R (U,4U) fp32 -> Rp with gate-interleaved columns: tile = blk (0..255),
// col c = gate*4 + du  ->  global col g = gate*1024 + blk*4 + du
__global__ __launch_bounds__(256) void pack_r(const float* __restrict__ R, u16* __restrict__ Rp) {
    size_t tid = (size_t)blockIdx.x * 256 + threadIdx.x;   // 256*32*64 = 524,288
    int L = (int)(tid & 63);
    size_t bkkb = tid >> 6;
    int kb  = (int)(bkkb & 31);
    int blk = (int)(bkkb >> 5);
    int c = L & 15;
    int gate = c >> 2, du = c & 3;
    int g = gate * 1024 + blk * 4 + du;
    int k0 = kb * 32 + (L >> 4) * 8;
    short8 v;
#pragma unroll
    for (int j = 0; j < 8; ++j) v[j] = (short)f2bf(R[(size_t)(k0 + j) * Gsz + g]);
    *(short8*)(Rp + tid * 8) = v;
}

// =====================================================================
// GEMM1: x_proj[t][b][g] = (X @ W)[m=b*T+t][g], bf16 MFMA, 128x128 tile.
// Grid: 128 m-blocks x 32 n-blocks. 256 threads = 4 waves, each 64x64.
// =====================================================================
__global__ __launch_bounds__(256) void gemm1(const u16* __restrict__ Af, const u16* __restrict__ Bf,
                                             float* __restrict__ xpf, u16* __restrict__ xph, int xp32) {
    __shared__ u16 smem[16 * 512];   // 16 chunks x 1KB (8 A-tiles + 8 B-tiles)
    int bm = blockIdx.x >> 5;        // 0..127
    int bn = blockIdx.x & 31;        // 0..31
    int tid = threadIdx.x;
    int w = tid >> 6, ln = tid & 63;
    int mw = w & 1, nw = w >> 1;

    f32x4 acc[4][4];
#pragma unroll
    for (int i = 0; i < 4; ++i)
#pragma unroll
        for (int j = 0; j < 4; ++j) acc[i][j] = (f32x4){0.f, 0.f, 0.f, 0.f};

    for (int kb = 0; kb < 32; ++kb) {
        // stage 16KB: wave w stages chunks 4w..4w+3 (reg round-trip this round)
        short8 tmp[4];
#pragma unroll
        for (int c2 = 0; c2 < 4; ++c2) {
            int chunk = w * 4 + c2;
            const u16* src = (chunk < 8)
                ? Af + (((size_t)(bm * 8 + chunk) * 32 + kb) * 64 + ln) * 8
                : Bf + (((size_t)(bn * 8 + (chunk - 8)) * 32 + kb) * 64 + ln) * 8;
            tmp[c2] = *(const short8*)src;
        }
#pragma unroll
        for (int c2 = 0; c2 < 4; ++c2) {
            int chunk = w * 4 + c2;
            *(short8*)(smem + chunk * 512 + ln * 8) = tmp[c2];
        }
        __syncthreads();
        short8 av[4], bv[4];
#pragma unroll
        for (int i = 0; i < 4; ++i) av[i] = *(const short8*)(smem + (mw * 4 + i) * 512 + ln * 8);
#pragma unroll
        for (int j = 0; j < 4; ++j) bv[j] = *(const short8*)(smem + (8 + nw * 4 + j) * 512 + ln * 8);
#pragma unroll
        for (int i = 0; i < 4; ++i)
#pragma unroll
            for (int j = 0; j < 4; ++j)
                acc[i][j] = __builtin_amdgcn_mfma_f32_16x16x32_bf16(av[i], bv[j], acc[i][j], 0, 0, 0);
        __syncthreads();
    }

    int quad = ln >> 4, c15 = ln & 15;
#pragma unroll
    for (int i = 0; i < 4; ++i) {
        int mt_g = bm * 8 + mw * 4 + i;
#pragma unroll
        for (int j = 0; j < 4; ++j) {
            int col = (bn * 8 + nw * 4 + j) * 16 + c15;
#pragma unroll
            for (int r = 0; r < 4; ++r) {
                int row = mt_g * 16 + quad * 4 + r;       // m = b*T + t
                int bb = row >> 9, tt = row & 511;
                size_t o = ((size_t)tt * Bsz + bb) * Gsz + col;
                if (xp32) xpf[o] = acc[i][j][r];
                else      xph[o] = f2bf(acc[i][j][r]);
            }
        }
    }
}

// =====================================================================
// Scan: cooperative persistent kernel, 256 blocks x 256 threads.
// Block blk owns units u = 4*blk..4*blk+3 (16 proj cols via Rp permutation).
// Waves: w&1 = M-tile (batch 0-15 / 16-31), w>>1 = K-half. LDS reduce.
// Threads 0..127 keep c,n,m in registers; h broadcast via global bf16 buf.
// =====================================================================
__global__ __launch_bounds__(256) void scan_all(const float* __restrict__ xpf, const u16* __restrict__ xph,
                                                int xp32, const u16* __restrict__ Rp,
                                                const float* __restrict__ bias,
                                                u16* __restrict__ hbf, float* __restrict__ out) {
    cg::grid_group grid = cg::this_grid();
    __shared__ float partial[2][64][4];
    __shared__ float proj[32][17];   // +1 pad: phase-B reads stride 17 banks

    int tid = threadIdx.x;
    int blk = blockIdx.x;
    int w = tid >> 6, ln = tid & 63, quad = ln >> 4, c15 = ln & 15;
    int mt = w & 1, kh = w >> 1;
    bool upd = (tid < 128);          // waves 0,1 exactly -> wave-uniform
    int b_row = tid >> 2, du = tid & 3;
    int u_g = blk * 4 + du;

    float bi[4] = {0.f, 0.f, 0.f, 0.f};
    float cs = 0.f, ns = 0.f, ms = 0.f;
    if (upd) {
#pragma unroll
        for (int g = 0; g < 4; ++g) bi[g] = bias[g * 1024 + u_g];
        hbf[b_row * Usz + u_g] = 0;  // zero-init h across the grid
    }
    grid.sync();

    const u16* aB = hbf + (size_t)(mt * 16 + c15) * Usz + quad * 8;
    const u16* bB = Rp + ((size_t)blk * 32 * 64 + ln) * 8;

    for (int t = 0; t < Tsz; ++t) {
        // prefetch x_proj slice (hides HBM latency behind MFMA phase)
        float xpv[4] = {0.f, 0.f, 0.f, 0.f};
        if (upd) {
            size_t o = ((size_t)t * Bsz + b_row) * Gsz + u_g;
#pragma unroll
            for (int g = 0; g < 4; ++g)
                xpv[g] = xp32 ? xpf[o + g * 1024] : bf2f(xph[o + g * 1024]);
        }

        f32x4 acc = (f32x4){0.f, 0.f, 0.f, 0.f};
#pragma unroll
        for (int kk = 0; kk < 16; ++kk) {
            int kb = kh * 16 + kk;
            short8 a = *(const short8*)(aB + kb * 32);
            short8 b = *(const short8*)(bB + (size_t)kb * 512);
            acc = __builtin_amdgcn_mfma_f32_16x16x32_bf16(a, b, acc, 0, 0, 0);
        }
        if (w >= 2) *(f32x4*)(&partial[w - 2][ln][0]) = acc;
        __syncthreads();
        if (w < 2) {
            f32x4 p = *(const f32x4*)(&partial[w][ln][0]);
#pragma unroll
            for (int r = 0; r < 4; ++r) proj[mt * 16 + quad * 4 + r][c15] = acc[r] + p[r];
        }
        __syncthreads();
        if (upd) {
            float ip = proj[b_row][du]      + xpv[0] + bi[0];
            float fp = proj[b_row][4 + du]  + xpv[1] + bi[1];
            float op = proj[b_row][8 + du]  + xpv[2] + bi[2];
            float zp = proj[b_row][12 + du] + xpv[3] + bi[3];
            float sf = 1.f / (1.f + __expf(-fp));
            float lf = __logf(sf + 1e-8f);
            float mn = fmaxf(ms + lf, ip);
            float it = __expf(ip - mn);
            float ft = __expf(ms + lf - mn);
            float ot = 1.f / (1.f + __expf(-op));
            float zt = tanhf(zp);
            cs = ft * cs + it * zt;
            ns = ft * ns + it;
            ms = mn;
            float h = ot * (cs / (ns + 1e-8f));
            out[(size_t)b_row * (Tsz * Usz) + (size_t)t * Usz + u_g] = h;
            hbf[b_row * Usz + u_g] = f2bf(h);
        }
        __threadfence();
        grid.sync();
    }
}

// =====================================================================
extern "C" void kernel_launch(void* const* d_in, const int* in_sizes, int n_in,
                              void* d_out, int out_size, void* d_ws, size_t ws_size,
                              hipStream_t stream) {
    const float* x    = (const float*)d_in[0];   // (B,T,D)
    const float* W    = (const float*)d_in[1];   // (D,4U)
    const float* R    = (const float*)d_in[2];   // (U,4U)
    const float* bias = (const float*)d_in[3];   // (4U,)
    float* out = (float*)d_out;

    char* ws = (char*)d_ws;
    size_t off = 0;
    u16* Af = (u16*)(ws + off); off += (size_t)16384 * 1024 * 2;  // 32MB
    u16* Bf = (u16*)(ws + off); off += (size_t)1024 * 4096 * 2;   // 8MB
    u16* Rp = (u16*)(ws + off); off += (size_t)1024 * 4096 * 2;   // 8MB
    u16* hbf = (u16*)(ws + off); off += (size_t)1 << 20;          // 1MB (uses 64KB)
    size_t xp_need32 = (size_t)16384 * 4096 * 4;                  // 256MB
    int xp32 = (ws_size >= off + xp_need32) ? 1 : 0;
    float* xpf = (float*)(ws + off);
    u16*   xph = (u16*)(ws + off);

    pack_a<<<dim3(8192), dim3(256), 0, stream>>>(x, Af);
    pack_b<<<dim3(2048), dim3(256), 0, stream>>>(W, Bf);
    pack_r<<<dim3(2048), dim3(256), 0, stream>>>(R, Rp);
    gemm1<<<dim3(4096), dim3(256), 0, stream>>>(Af, Bf, xpf, xph, xp32);

    void* args[] = { (void*)&xpf, (void*)&xph, (void*)&xp32, (void*)&Rp,
                     (void*)&bias, (void*)&hbf, (void*)&out };
    hipLaunchCooperativeKernel((const void*)scan_all, dim3(256), dim3(256), args, 0, stream);
}

// Round 2
// 11609.152 us; speedup vs baseline: 2.7707x; 2.7707x over previous
//
#include <hip/hip_runtime.h>
#include <hip/hip_cooperative_groups.h>

typedef unsigned short u16;
typedef short short8 __attribute__((ext_vector_type(8)));
typedef float f32x4 __attribute__((ext_vector_type(4)));

#define Bsz 32
#define Tsz 512
#define Dsz 1024
#define Usz 1024
#define Gsz 4096   // 4*U

// ---- bf16 helpers (manual RNE) ----
static __device__ __forceinline__ u16 f2bf(float f) {
    unsigned int u = __float_as_uint(f);
    unsigned int lsb = (u >> 16) & 1u;
    u += 0x7fffu + lsb;
    return (u16)(u >> 16);
}
static __device__ __forceinline__ float bf2f(u16 b) {
    return __uint_as_float(((unsigned int)b) << 16);
}

// Custom grid barrier: monotone epoch counter, release-add + relaxed spin.
// All 256 blocks are co-resident (cooperative launch), so spinning is safe.
static __device__ __forceinline__ void grid_barrier(unsigned* cnt, unsigned target) {
    __syncthreads();                         // all waves' stores issued & vmcnt-drained
    if (threadIdx.x == 0) {
        __builtin_amdgcn_fence(__ATOMIC_RELEASE, "agent");   // wbl2: push dirty L2 (h) to LLC
        __hip_atomic_fetch_add(cnt, 1u, __ATOMIC_RELAXED, __HIP_MEMORY_SCOPE_AGENT);
        while (__hip_atomic_load(cnt, __ATOMIC_RELAXED, __HIP_MEMORY_SCOPE_AGENT) < target)
            __builtin_amdgcn_s_sleep(1);
    }
    __syncthreads();
    __builtin_amdgcn_fence(__ATOMIC_ACQUIRE, "agent");       // inv L1/L2 so h reads are fresh
}

// =====================================================================
// Pack kernels: MFMA-fragment-ordered bf16 buffers.
// A-frag (16x16x32): lane L holds A[m = mt*16 + (L&15)][k = kb*32 + (L>>4)*8 + j]
// B-frag:            lane L holds B[k = kb*32 + (L>>4)*8 + j][n = nt*16 + (L&15)]
// Flat: buf[((tile*32 + kb)*64 + L)*8 + j] -> lane-contiguous 16B chunks.
// =====================================================================

__global__ __launch_bounds__(256) void pack_a(const float* __restrict__ x, u16* __restrict__ Af) {
    size_t tid = (size_t)blockIdx.x * 256 + threadIdx.x;
    int L = (int)(tid & 63);
    size_t mtkb = tid >> 6;
    int kb = (int)(mtkb & 31);
    int mt = (int)(mtkb >> 5);
    int m  = mt * 16 + (L & 15);
    int d0 = kb * 32 + (L >> 4) * 8;
    const float* src = x + (size_t)m * Dsz + d0;
    short8 v;
#pragma unroll
    for (int j = 0; j < 8; ++j) v[j] = (short)f2bf(src[j]);
    *(short8*)(Af + tid * 8) = v;
}

__global__ __launch_bounds__(256) void pack_b(const float* __restrict__ W, u16* __restrict__ Bf) {
    size_t tid = (size_t)blockIdx.x * 256 + threadIdx.x;
    int L = (int)(tid & 63);
    size_t ntkb = tid >> 6;
    int kb = (int)(ntkb & 31);
    int nt = (int)(ntkb >> 5);
    int n  = nt * 16 + (L & 15);
    int k0 = kb * 32 + (L >> 4) * 8;
    short8 v;
#pragma unroll
    for (int j = 0; j < 8; ++j) v[j] = (short)f2bf(W[(size_t)(k0 + j) * Gsz + n]);
    *(short8*)(Bf + tid * 8) = v;
}

// R -> Rp gate-interleaved: tile=blk, col c=gate*4+du -> g=gate*1024+blk*4+du.
// Also zeroes the barrier counter (ws is poisoned before every call).
__global__ __launch_bounds__(256) void pack_r(const float* __restrict__ R, u16* __restrict__ Rp,
                                              unsigned* __restrict__ cnt) {
    if (blockIdx.x == 0 && threadIdx.x == 0) *cnt = 0;
    size_t tid = (size_t)blockIdx.x * 256 + threadIdx.x;
    int L = (int)(tid & 63);
    size_t bkkb = tid >> 6;
    int kb  = (int)(bkkb & 31);
    int blk = (int)(bkkb >> 5);
    int c = L & 15;
    int gate = c >> 2, du = c & 3;
    int g = gate * 1024 + blk * 4 + du;
    int k0 = kb * 32 + (L >> 4) * 8;
    short8 v;
#pragma unroll
    for (int j = 0; j < 8; ++j) v[j] = (short)f2bf(R[(size_t)(k0 + j) * Gsz + g]);
    *(short8*)(Rp + tid * 8) = v;
}

// =====================================================================
// GEMM1: x_proj[t][b][g] = (X @ W)[m=b*T+t][g]; 128x128 tile, 4 waves.
// =====================================================================
__global__ __launch_bounds__(256) void gemm1(const u16* __restrict__ Af, const u16* __restrict__ Bf,
                                             float* __restrict__ xpf, u16* __restrict__ xph, int xp32) {
    __shared__ u16 smem[16 * 512];
    int bm = blockIdx.x >> 5;
    int bn = blockIdx.x & 31;
    int tid = threadIdx.x;
    int w = tid >> 6, ln = tid & 63;
    int mw = w & 1, nw = w >> 1;

    f32x4 acc[4][4];
#pragma unroll
    for (int i = 0; i < 4; ++i)
#pragma unroll
        for (int j = 0; j < 4; ++j) acc[i][j] = (f32x4){0.f, 0.f, 0.f, 0.f};

    for (int kb = 0; kb < 32; ++kb) {
        short8 tmp[4];
#pragma unroll
        for (int c2 = 0; c2 < 4; ++c2) {
            int chunk = w * 4 + c2;
            const u16* src = (chunk < 8)
                ? Af + (((size_t)(bm * 8 + chunk) * 32 + kb) * 64 + ln) * 8
                : Bf + (((size_t)(bn * 8 + (chunk - 8)) * 32 + kb) * 64 + ln) * 8;
            tmp[c2] = *(const short8*)src;
        }
#pragma unroll
        for (int c2 = 0; c2 < 4; ++c2) {
            int chunk = w * 4 + c2;
            *(short8*)(smem + chunk * 512 + ln * 8) = tmp[c2];
        }
        __syncthreads();
        short8 av[4], bv[4];
#pragma unroll
        for (int i = 0; i < 4; ++i) av[i] = *(const short8*)(smem + (mw * 4 + i) * 512 + ln * 8);
#pragma unroll
        for (int j = 0; j < 4; ++j) bv[j] = *(const short8*)(smem + (8 + nw * 4 + j) * 512 + ln * 8);
#pragma unroll
        for (int i = 0; i < 4; ++i)
#pragma unroll
            for (int j = 0; j < 4; ++j)
                acc[i][j] = __builtin_amdgcn_mfma_f32_16x16x32_bf16(av[i], bv[j], acc[i][j], 0, 0, 0);
        __syncthreads();
    }

    int quad = ln >> 4, c15 = ln & 15;
#pragma unroll
    for (int i = 0; i < 4; ++i) {
        int mt_g = bm * 8 + mw * 4 + i;
#pragma unroll
        for (int j = 0; j < 4; ++j) {
            int col = (bn * 8 + nw * 4 + j) * 16 + c15;
#pragma unroll
            for (int r = 0; r < 4; ++r) {
                int row = mt_g * 16 + quad * 4 + r;
                int bb = row >> 9, tt = row & 511;
                size_t o = ((size_t)tt * Bsz + bb) * Gsz + col;
                if (xp32) xpf[o] = acc[i][j][r];
                else      xph[o] = f2bf(acc[i][j][r]);
            }
        }
    }
}

// =====================================================================
// Scan: 256 blocks x 256 threads, custom barrier, double-buffered h.
// Block blk owns units 4*blk..4*blk+3 (16 Rp-permuted proj cols).
// Waves: w&1 = M-tile (batch half), w>>1 = K-half; LDS reduce.
// Rp fragments live in registers for the whole scan (acquire fence
// invalidates caches every step — anything hot must be in regs).
// =====================================================================
__global__ __launch_bounds__(256, 2) void scan_all(const float* __restrict__ xpf,
                                                   const u16* __restrict__ xph, int xp32,
                                                   const u16* __restrict__ Rp,
                                                   const float* __restrict__ bias,
                                                   u16* __restrict__ hbf, float* __restrict__ out,
                                                   unsigned* __restrict__ cnt) {
    __shared__ float partial[2][64][4];
    __shared__ float proj[32][17];

    int tid = threadIdx.x;
    int blk = blockIdx.x;
    int w = tid >> 6, ln = tid & 63, quad = ln >> 4, c15 = ln & 15;
    int mt = w & 1, kh = w >> 1;
    bool upd = (tid < 128);
    int b_row = tid >> 2, du = tid & 3;
    int u_g = blk * 4 + du;

    u16* hb0 = hbf;                 // written at even t
    u16* hb1 = hbf + 32 * 1024;     // written at odd t; read (zeros) at t=0

    // Preload constant B-fragments: 16 x short8 = 64 VGPRs.
    short8 bfr[16];
    const u16* bB = Rp + ((size_t)blk * 32 * 64 + ln) * 8;
#pragma unroll
    for (int kk = 0; kk < 16; ++kk)
        bfr[kk] = *(const short8*)(bB + (size_t)(kh * 16 + kk) * 512);

    float bi[4] = {0.f, 0.f, 0.f, 0.f};
    float cs = 0.f, ns = 0.f, ms = 0.f;
    if (upd) {
#pragma unroll
        for (int g = 0; g < 4; ++g) bi[g] = bias[g * 1024 + u_g];
        hb1[b_row * Usz + u_g] = 0;
    }
    unsigned ep = 256;
    grid_barrier(cnt, ep);

    for (int t = 0; t < Tsz; ++t) {
        const u16* rb = (t & 1) ? hb0 : hb1;   // h_{t-1}
        u16*       wbuf = (t & 1) ? hb1 : hb0; // h_t

        // prefetch x_proj slice early (HBM latency hidden behind MFMA)
        float xpv[4] = {0.f, 0.f, 0.f, 0.f};
        if (upd) {
            size_t o = ((size_t)t * Bsz + b_row) * Gsz + u_g;
#pragma unroll
            for (int g = 0; g < 4; ++g)
                xpv[g] = xp32 ? xpf[o + g * 1024] : bf2f(xph[o + g * 1024]);
        }

        const u16* aB = rb + (size_t)(mt * 16 + c15) * Usz + quad * 8;
        f32x4 acc = (f32x4){0.f, 0.f, 0.f, 0.f};
#pragma unroll
        for (int kk = 0; kk < 16; ++kk) {
            short8 a = *(const short8*)(aB + (kh * 16 + kk) * 32);
            acc = __builtin_amdgcn_mfma_f32_16x16x32_bf16(a, bfr[kk], acc, 0, 0, 0);
        }
        if (w >= 2) *(f32x4*)(&partial[w - 2][ln][0]) = acc;
        __syncthreads();
        if (w < 2) {
            f32x4 p = *(const f32x4*)(&partial[w][ln][0]);
#pragma unroll
            for (int r = 0; r < 4; ++r) proj[mt * 16 + quad * 4 + r][c15] = acc[r] + p[r];
        }
        __syncthreads();
        if (upd) {
            float ip = proj[b_row][du]      + xpv[0] + bi[0];
            float fp = proj[b_row][4 + du]  + xpv[1] + bi[1];
            float op = proj[b_row][8 + du]  + xpv[2] + bi[2];
            float zp = proj[b_row][12 + du] + xpv[3] + bi[3];
            float sf = 1.f / (1.f + __expf(-fp));
            float lf = __logf(sf + 1e-8f);
            float mn = fmaxf(ms + lf, ip);
            float it = __expf(ip - mn);
            float ft = __expf(ms + lf - mn);
            float ot = 1.f / (1.f + __expf(-op));
            float zt = tanhf(zp);
            cs = ft * cs + it * zt;
            ns = ft * ns + it;
            ms = mn;
            float h = ot * (cs / (ns + 1e-8f));
            out[(size_t)b_row * (Tsz * Usz) + (size_t)t * Usz + u_g] = h;
            wbuf[b_row * Usz + u_g] = f2bf(h);
        }
        ep += 256;
        grid_barrier(cnt, ep);
    }
}

// =====================================================================
extern "C" void kernel_launch(void* const* d_in, const int* in_sizes, int n_in,
                              void* d_out, int out_size, void* d_ws, size_t ws_size,
                              hipStream_t stream) {
    const float* x    = (const float*)d_in[0];
    const float* W    = (const float*)d_in[1];
    const float* R    = (const float*)d_in[2];
    const float* bias = (const float*)d_in[3];
    float* out = (float*)d_out;

    char* ws = (char*)d_ws;
    size_t off = 0;
    u16* Af = (u16*)(ws + off); off += (size_t)16384 * 1024 * 2;  // 32MB
    u16* Bf = (u16*)(ws + off); off += (size_t)1024 * 4096 * 2;   // 8MB
    u16* Rp = (u16*)(ws + off); off += (size_t)1024 * 4096 * 2;   // 8MB
    u16* hbf = (u16*)(ws + off); off += (size_t)1 << 20;          // 1MB (2x64KB used)
    unsigned* cnt = (unsigned*)(ws + off); off += 4096;           // barrier counter
    size_t xp_need32 = (size_t)16384 * 4096 * 4;                  // 256MB
    int xp32 = (ws_size >= off + xp_need32) ? 1 : 0;
    float* xpf = (float*)(ws + off);
    u16*   xph = (u16*)(ws + off);

    pack_a<<<dim3(8192), dim3(256), 0, stream>>>(x, Af);
    pack_b<<<dim3(2048), dim3(256), 0, stream>>>(W, Bf);
    pack_r<<<dim3(2048), dim3(256), 0, stream>>>(R, Rp, cnt);
    gemm1<<<dim3(4096), dim3(256), 0, stream>>>(Af, Bf, xpf, xph, xp32);

    void* args[] = { (void*)&xpf, (void*)&xph, (void*)&xp32, (void*)&Rp,
                     (void*)&bias, (void*)&hbf, (void*)&out, (void*)&cnt };
    hipLaunchCooperativeKernel((const void*)scan_all, dim3(256), dim3(256), args, 0, stream);
}

// Round 3
// 2812.342 us; speedup vs baseline: 11.4373x; 4.1279x over previous
//
#include <hip/hip_runtime.h>

typedef unsigned short u16;
typedef short short8 __attribute__((ext_vector_type(8)));
typedef float f32x4 __attribute__((ext_vector_type(4)));
typedef unsigned int u32x4 __attribute__((ext_vector_type(4)));
typedef unsigned short u16x4 __attribute__((ext_vector_type(4)));

#define Bsz 32
#define Tsz 512
#define Dsz 1024
#define Usz 1024
#define Gsz 4096   // 4*U

// ---- bf16 helpers (manual RNE) ----
static __device__ __forceinline__ u16 f2bf(float f) {
    unsigned int u = __float_as_uint(f);
    unsigned int lsb = (u >> 16) & 1u;
    u += 0x7fffu + lsb;
    return (u16)(u >> 16);
}
static __device__ __forceinline__ float bf2f(u16 b) {
    return __uint_as_float(((unsigned int)b) << 16);
}

// =====================================================================
// Pack kernels: MFMA-fragment-ordered bf16 buffers.
// A-frag (16x16x32): lane L holds A[m = mt*16 + (L&15)][k = kb*32 + (L>>4)*8 + j]
// B-frag:            lane L holds B[k = kb*32 + (L>>4)*8 + j][n = nt*16 + (L&15)]
// Flat: buf[((tile*32 + kb)*64 + L)*8 + j] -> lane-contiguous 16B chunks.
// =====================================================================

__global__ __launch_bounds__(256) void pack_a(const float* __restrict__ x, u16* __restrict__ Af) {
    size_t tid = (size_t)blockIdx.x * 256 + threadIdx.x;
    int L = (int)(tid & 63);
    size_t mtkb = tid >> 6;
    int kb = (int)(mtkb & 31);
    int mt = (int)(mtkb >> 5);
    int m  = mt * 16 + (L & 15);
    int d0 = kb * 32 + (L >> 4) * 8;
    const float* src = x + (size_t)m * Dsz + d0;
    short8 v;
#pragma unroll
    for (int j = 0; j < 8; ++j) v[j] = (short)f2bf(src[j]);
    *(short8*)(Af + tid * 8) = v;
}

__global__ __launch_bounds__(256) void pack_b(const float* __restrict__ W, u16* __restrict__ Bf) {
    size_t tid = (size_t)blockIdx.x * 256 + threadIdx.x;
    int L = (int)(tid & 63);
    size_t ntkb = tid >> 6;
    int kb = (int)(ntkb & 31);
    int nt = (int)(ntkb >> 5);
    int n  = nt * 16 + (L & 15);
    int k0 = kb * 32 + (L >> 4) * 8;
    short8 v;
#pragma unroll
    for (int j = 0; j < 8; ++j) v[j] = (short)f2bf(W[(size_t)(k0 + j) * Gsz + n]);
    *(short8*)(Bf + tid * 8) = v;
}

// R -> Rp gate-interleaved: tile=blk, col c=gate*4+du -> g=gate*1024+blk*4+du.
// Also zeroes the 256 barrier flags (ws is poisoned 0xAA before every call!).
__global__ __launch_bounds__(256) void pack_r(const float* __restrict__ R, u16* __restrict__ Rp,
                                              unsigned* __restrict__ flags) {
    if (blockIdx.x == 0) flags[threadIdx.x] = 0;
    size_t tid = (size_t)blockIdx.x * 256 + threadIdx.x;
    int L = (int)(tid & 63);
    size_t bkkb = tid >> 6;
    int kb  = (int)(bkkb & 31);
    int blk = (int)(bkkb >> 5);
    int c = L & 15;
    int gate = c >> 2, du = c & 3;
    int g = gate * 1024 + blk * 4 + du;
    int k0 = kb * 32 + (L >> 4) * 8;
    short8 v;
#pragma unroll
    for (int j = 0; j < 8; ++j) v[j] = (short)f2bf(R[(size_t)(k0 + j) * Gsz + g]);
    *(short8*)(Rp + tid * 8) = v;
}

// =====================================================================
// GEMM1: x_proj = X @ W; 128x128 tile, 4 waves. Epilogue writes the
// scan-friendly layout: [t][b][blk(256)][du(4)][gate(4)] so each scan
// block reads exactly one 64B line per (t,b).
// =====================================================================
__global__ __launch_bounds__(256) void gemm1(const u16* __restrict__ Af, const u16* __restrict__ Bf,
                                             float* __restrict__ xpf, u16* __restrict__ xph, int xp32) {
    __shared__ u16 smem[16 * 512];
    int bm = blockIdx.x >> 5;
    int bn = blockIdx.x & 31;
    int tid = threadIdx.x;
    int w = tid >> 6, ln = tid & 63;
    int mw = w & 1, nw = w >> 1;

    f32x4 acc[4][4];
#pragma unroll
    for (int i = 0; i < 4; ++i)
#pragma unroll
        for (int j = 0; j < 4; ++j) acc[i][j] = (f32x4){0.f, 0.f, 0.f, 0.f};

    for (int kb = 0; kb < 32; ++kb) {
        short8 tmp[4];
#pragma unroll
        for (int c2 = 0; c2 < 4; ++c2) {
            int chunk = w * 4 + c2;
            const u16* src = (chunk < 8)
                ? Af + (((size_t)(bm * 8 + chunk) * 32 + kb) * 64 + ln) * 8
                : Bf + (((size_t)(bn * 8 + (chunk - 8)) * 32 + kb) * 64 + ln) * 8;
            tmp[c2] = *(const short8*)src;
        }
#pragma unroll
        for (int c2 = 0; c2 < 4; ++c2) {
            int chunk = w * 4 + c2;
            *(short8*)(smem + chunk * 512 + ln * 8) = tmp[c2];
        }
        __syncthreads();
        short8 av[4], bv[4];
#pragma unroll
        for (int i = 0; i < 4; ++i) av[i] = *(const short8*)(smem + (mw * 4 + i) * 512 + ln * 8);
#pragma unroll
        for (int j = 0; j < 4; ++j) bv[j] = *(const short8*)(smem + (8 + nw * 4 + j) * 512 + ln * 8);
#pragma unroll
        for (int i = 0; i < 4; ++i)
#pragma unroll
            for (int j = 0; j < 4; ++j)
                acc[i][j] = __builtin_amdgcn_mfma_f32_16x16x32_bf16(av[i], bv[j], acc[i][j], 0, 0, 0);
        __syncthreads();
    }

    int quad = ln >> 4, c15 = ln & 15;
#pragma unroll
    for (int i = 0; i < 4; ++i) {
        int mt_g = bm * 8 + mw * 4 + i;
#pragma unroll
        for (int j = 0; j < 4; ++j) {
            int g = (bn * 8 + nw * 4 + j) * 16 + c15;
            int p = ((g & 1023) >> 2) * 16 + (g & 3) * 4 + (g >> 10);
#pragma unroll
            for (int r = 0; r < 4; ++r) {
                int row = mt_g * 16 + quad * 4 + r;
                int bb = row >> 9, tt = row & 511;
                size_t o = ((size_t)tt * Bsz + bb) * Gsz + p;
                if (xp32) xpf[o] = acc[i][j][r];
                else      xph[o] = f2bf(acc[i][j][r]);
            }
        }
    }
}

// =====================================================================
// Scan: 256 blocks x 256 threads. No fences: h + flags go through LLC
// via sc0/sc1 (cache-bypass) asm ops; Rp lives in LDS; x_proj is
// prefetched one step ahead through the normal cached path.
// Protocol per step: [poll flags >= t+1] -> bypass-load h_{t-1} ->
// MFMA -> LDS reduce -> gates -> bypass-store h_t -> vmcnt(0)/barrier
// -> flag = t+2.  Double-buffered h (flags are one-sided).
// =====================================================================
__global__ __launch_bounds__(256) void scan_all(const float* __restrict__ xpf,
                                                const u16* __restrict__ xph, int xp32,
                                                const u16* __restrict__ Rp,
                                                const float* __restrict__ bias,
                                                u16* __restrict__ hbf, float* __restrict__ out,
                                                unsigned* __restrict__ flags) {
    __shared__ u16 lds_r[16384];          // 32KB: this block's Rp slice
    __shared__ float partial[2][64][4];
    __shared__ float proj[32][17];

    int tid = threadIdx.x;
    int blk = blockIdx.x;
    int w = tid >> 6, ln = tid & 63, quad = ln >> 4, c15 = ln & 15;
    int mt = w & 1, kh = w >> 1;
    bool upd = (tid < 128);               // waves 0,1 -> wave-uniform
    int b_row = tid >> 2, du = tid & 3;
    int u_g = blk * 4 + du;

    u16* hb0 = hbf;                       // written at even t
    u16* hb1 = hbf + 32 * 1024;           // written at odd t; zeros for t=0

    // ---- stage Rp slice into LDS (fragment order preserved) ----
    const u16* rsrc = Rp + (size_t)blk * 16384;
#pragma unroll
    for (int i = 0; i < 8; ++i)
        *(short8*)(lds_r + tid * 64 + i * 8) = *(const short8*)(rsrc + tid * 64 + i * 8);

    float bi[4] = {0.f, 0.f, 0.f, 0.f};
    float cs = 0.f, ns = 0.f, ms = 0.f;
    float xpn0 = 0.f, xpn1 = 0.f, xpn2 = 0.f, xpn3 = 0.f;

    if (upd) {
#pragma unroll
        for (int g = 0; g < 4; ++g) bi[g] = bias[g * 1024 + u_g];
        // init h_{-1} = 0 in hb1 (bypass store -> LLC)
        u16* hp = hb1 + b_row * Usz + u_g;
        unsigned z = 0;
        asm volatile("global_store_short %0, %1, off sc0 sc1" :: "v"(hp), "v"(z) : "memory");
        // prefetch x_proj slice for t=0
        size_t o0 = ((size_t)0 * Bsz + b_row) * Gsz + blk * 16 + du * 4;
        if (xp32) { float4 v4 = *(const float4*)(xpf + o0); xpn0 = v4.x; xpn1 = v4.y; xpn2 = v4.z; xpn3 = v4.w; }
        else      { u16x4 v = *(const u16x4*)(xph + o0); xpn0 = bf2f(v[0]); xpn1 = bf2f(v[1]); xpn2 = bf2f(v[2]); xpn3 = bf2f(v[3]); }
    }
    asm volatile("s_waitcnt vmcnt(0)" ::: "memory");
    __syncthreads();
    if (tid == 0) {
        unsigned* fp = flags + blk;
        unsigned one = 1;
        asm volatile("global_store_dword %0, %1, off sc0 sc1" :: "v"(fp), "v"(one) : "memory");
    }

    // per-wave constant h-fragment base (byte offsets kk*64 added as imm)
    const u16* aB0 = hb0 + (size_t)(mt * 16 + c15) * Usz + quad * 8 + kh * 512;
    const u16* aB1 = hb1 + (size_t)(mt * 16 + c15) * Usz + quad * 8 + kh * 512;

    for (int t = 0; t < Tsz; ++t) {
        // ---- distributed barrier: wave0 polls all 256 flags (4/lane) ----
        if (w == 0) {
            const unsigned* fp4 = flags + ln * 4;
            unsigned tgt = (unsigned)(t + 1);
            u32x4 fv;
            do {
                asm volatile("global_load_dwordx4 %0, %1, off sc0 sc1\n\ts_waitcnt vmcnt(0)"
                             : "=v"(fv) : "v"(fp4) : "memory");
            } while (__any((int)(fv[0] < tgt || fv[1] < tgt || fv[2] < tgt || fv[3] < tgt)));
        }
        __syncthreads();

        // consume prefetched x_proj; immediately prefetch t+1 (overlaps everything)
        float xv0 = xpn0, xv1 = xpn1, xv2 = xpn2, xv3 = xpn3;
        if (upd) {
            int tn = (t + 1 < Tsz) ? t + 1 : t;
            size_t o = ((size_t)tn * Bsz + b_row) * Gsz + blk * 16 + du * 4;
            if (xp32) { float4 v4 = *(const float4*)(xpf + o); xpn0 = v4.x; xpn1 = v4.y; xpn2 = v4.z; xpn3 = v4.w; }
            else      { u16x4 v = *(const u16x4*)(xph + o); xpn0 = bf2f(v[0]); xpn1 = bf2f(v[1]); xpn2 = bf2f(v[2]); xpn3 = bf2f(v[3]); }
        }

        // ---- bypass-load h_{t-1} fragments (16 x 16B per lane) ----
        const u16* aBw = (t & 1) ? aB0 : aB1;
        short8 av[16];
#define LDH(i, OFF) asm volatile("global_load_dwordx4 %0, %1, off offset:" OFF " sc0 sc1" \
                                 : "=v"(av[i]) : "v"(aBw))
        LDH(0, "0");   LDH(1, "64");  LDH(2, "128"); LDH(3, "192");
        LDH(4, "256"); LDH(5, "320"); LDH(6, "384"); LDH(7, "448");
        LDH(8, "512"); LDH(9, "576"); LDH(10, "640"); LDH(11, "704");
        LDH(12, "768"); LDH(13, "832"); LDH(14, "896"); LDH(15, "960");
#undef LDH
        asm volatile("s_waitcnt vmcnt(0)" ::: "memory");

        // ---- MFMA: two independent chains to halve dependency latency ----
        f32x4 acc0 = (f32x4){0.f, 0.f, 0.f, 0.f};
        f32x4 acc1 = (f32x4){0.f, 0.f, 0.f, 0.f};
#pragma unroll
        for (int kk = 0; kk < 16; kk += 2) {
            short8 b0 = *(const short8*)(lds_r + ((kh * 16 + kk) * 64 + ln) * 8);
            short8 b1 = *(const short8*)(lds_r + ((kh * 16 + kk + 1) * 64 + ln) * 8);
            acc0 = __builtin_amdgcn_mfma_f32_16x16x32_bf16(av[kk], b0, acc0, 0, 0, 0);
            acc1 = __builtin_amdgcn_mfma_f32_16x16x32_bf16(av[kk + 1], b1, acc1, 0, 0, 0);
        }
        f32x4 acc = acc0 + acc1;

        if (w >= 2) *(f32x4*)(&partial[w - 2][ln][0]) = acc;
        __syncthreads();
        if (w < 2) {
            f32x4 p = *(const f32x4*)(&partial[w][ln][0]);
#pragma unroll
            for (int r = 0; r < 4; ++r) proj[mt * 16 + quad * 4 + r][c15] = acc[r] + p[r];
        }
        __syncthreads();

        if (upd) {
            float ip = proj[b_row][du]      + xv0 + bi[0];
            float fp = proj[b_row][4 + du]  + xv1 + bi[1];
            float op = proj[b_row][8 + du]  + xv2 + bi[2];
            float zp = proj[b_row][12 + du] + xv3 + bi[3];
            float sf = 1.f / (1.f + __expf(-fp));
            float lf = __logf(sf + 1e-8f);
            float mn = fmaxf(ms + lf, ip);
            float it = __expf(ip - mn);
            float ft = __expf(ms + lf - mn);
            float ot = 1.f / (1.f + __expf(-op));
            float zt = tanhf(zp);
            cs = ft * cs + it * zt;
            ns = ft * ns + it;
            ms = mn;
            float h = ot * (cs / (ns + 1e-8f));
            out[(size_t)b_row * (Tsz * Usz) + (size_t)t * Usz + u_g] = h;   // plain (flushed at kernel end)
            u16* hp = ((t & 1) ? hb1 : hb0) + b_row * Usz + u_g;
            unsigned hv = (unsigned)f2bf(h);
            asm volatile("global_store_short %0, %1, off sc0 sc1" :: "v"(hp), "v"(hv) : "memory");
        }
        asm volatile("s_waitcnt vmcnt(0)" ::: "memory");   // per-wave: h stores are in LLC
        __syncthreads();                                   // all waves drained
        if (tid == 0) {
            unsigned* fp = flags + blk;
            unsigned val = (unsigned)(t + 2);
            asm volatile("global_store_dword %0, %1, off sc0 sc1" :: "v"(fp), "v"(val) : "memory");
        }
    }
}

// =====================================================================
extern "C" void kernel_launch(void* const* d_in, const int* in_sizes, int n_in,
                              void* d_out, int out_size, void* d_ws, size_t ws_size,
                              hipStream_t stream) {
    const float* x    = (const float*)d_in[0];
    const float* W    = (const float*)d_in[1];
    const float* R    = (const float*)d_in[2];
    const float* bias = (const float*)d_in[3];
    float* out = (float*)d_out;

    char* ws = (char*)d_ws;
    size_t off = 0;
    u16* Af = (u16*)(ws + off); off += (size_t)16384 * 1024 * 2;  // 32MB
    u16* Bf = (u16*)(ws + off); off += (size_t)1024 * 4096 * 2;   // 8MB
    u16* Rp = (u16*)(ws + off); off += (size_t)1024 * 4096 * 2;   // 8MB
    u16* hbf = (u16*)(ws + off); off += (size_t)1 << 20;          // 1MB (2x64KB used)
    unsigned* flags = (unsigned*)(ws + off); off += 4096;         // 256 flags
    size_t xp_need32 = (size_t)16384 * 4096 * 4;                  // 256MB
    int xp32 = (ws_size >= off + xp_need32) ? 1 : 0;
    float* xpf = (float*)(ws + off);
    u16*   xph = (u16*)(ws + off);

    pack_a<<<dim3(8192), dim3(256), 0, stream>>>(x, Af);
    pack_b<<<dim3(2048), dim3(256), 0, stream>>>(W, Bf);
    pack_r<<<dim3(2048), dim3(256), 0, stream>>>(R, Rp, flags);
    gemm1<<<dim3(4096), dim3(256), 0, stream>>>(Af, Bf, xpf, xph, xp32);

    void* args[] = { (void*)&xpf, (void*)&xph, (void*)&xp32, (void*)&Rp,
                     (void*)&bias, (void*)&hbf, (void*)&out, (void*)&flags };
    hipLaunchCooperativeKernel((const void*)scan_all, dim3(256), dim3(256), args, 0, stream);
}